// Round 1
// baseline (302.568 us; speedup 1.0000x reference)
//
#include <hip/hip_runtime.h>

// FP8 E4M3 bit-level multiplier.
// Inputs: a, b — float32 arrays of shape (1024, 4096, 8), each last-dim group
// is the bit vector [s, e3, e2, e1, e0, m2, m1, m0] with values 0.0f/1.0f.
// Output: same bit-vector format for the RNE-rounded FP8 product, with
// subnormal, NaN-on-overflow, and zero handling per the reference.

#define BIAS 7

__device__ __forceinline__ int rne_rshift(int M, int sh) {
    // round-to-nearest-even right shift of non-negative M by sh >= 0
    int q = M >> sh;
    int rem = M - (q << sh);
    int half = (1 << sh) >> 1;           // 2^(sh-1), 0 when sh==0
    int up = ((rem > half) | ((rem == half) & (q & 1))) & (sh > 0);
    return q + up;
}

__global__ void __launch_bounds__(256)
fp8_mul_kernel(const float4* __restrict__ a, const float4* __restrict__ b,
               float4* __restrict__ out, int n_groups) {
    int i = blockIdx.x * blockDim.x + threadIdx.x;
    if (i >= n_groups) return;

    float4 a0 = a[2 * i];
    float4 a1 = a[2 * i + 1];
    float4 b0 = b[2 * i];
    float4 b1 = b[2 * i + 1];

    // decode (bits are exactly 0.0f or 1.0f)
    int sa = (int)a0.x;
    int ea = ((int)a0.y << 3) | ((int)a0.z << 2) | ((int)a0.w << 1) | (int)a1.x;
    int ma = ((int)a1.y << 2) | ((int)a1.z << 1) | (int)a1.w;
    int sb = (int)b0.x;
    int eb = ((int)b0.y << 3) | ((int)b0.z << 2) | ((int)b0.w << 1) | (int)b1.x;
    int mb = ((int)b1.y << 2) | ((int)b1.z << 1) | (int)b1.w;

    // significand with implicit bit; subnormals use (e=1, no implicit bit)
    int sig_a = (ea == 0) ? ma : (ma + 8);
    int sig_b = (eb == 0) ? mb : (mb + 8);
    int exa = ((ea == 0) ? 1 : ea) - BIAS;
    int exb = ((eb == 0) ? 1 : eb) - BIAS;

    int M = sig_a * sig_b;              // exact product, <= 225
    int E = exa + exb - 6;              // value = M * 2^E

    // MSB position p of M (p in [0,7]); M==0 handled by the zero mux below
    int p = (M > 0) ? (31 - __clz(M)) : 0;
    int eb_out = E + p + BIAS;          // candidate biased exponent

    // ---- normal path (eb_out >= 1): RNE round to 3 mantissa bits ----
    int sh  = p - 3;
    int shp = (sh > 0) ? sh : 0;
    int lsh = (sh < 0) ? -sh : 0;
    int mant4 = rne_rshift(M, shp) << lsh;   // in [8, 16]
    int carry = mant4 >> 4;                  // rounding overflow -> exp += 1
    if (mant4 == 16) mant4 = 8;
    int e_n = eb_out + carry;
    int m_n = mant4 - 8;
    if (e_n >= 16) { e_n = 15; m_n = 7; }    // overflow -> NaN

    // ---- subnormal path (eb_out <= 0): mant = RNE(M * 2^(E+9)) ----
    int t = E + 9;
    int rsh = (-t < 0) ? 0 : ((-t > 30) ? 30 : -t);
    int lsh_s = (t > 0) ? t : 0;
    int mant_s = rne_rshift(M, rsh) << lsh_s;
    int e_s = (mant_s >= 8) ? 1 : 0;         // rounding promoted to smallest normal
    int m_s = (mant_s >= 8) ? 0 : mant_s;

    // ---- select ----
    int is_sub = (eb_out <= 0);
    int e_o = is_sub ? e_s : e_n;
    int m_o = is_sub ? m_s : m_n;
    if (M == 0) { e_o = 0; m_o = 0; }        // either input true zero
    int s_o = sa ^ sb;

    float4 o0, o1;
    o0.x = (float)s_o;
    o0.y = (float)((e_o >> 3) & 1);
    o0.z = (float)((e_o >> 2) & 1);
    o0.w = (float)((e_o >> 1) & 1);
    o1.x = (float)(e_o & 1);
    o1.y = (float)((m_o >> 2) & 1);
    o1.z = (float)((m_o >> 1) & 1);
    o1.w = (float)(m_o & 1);
    out[2 * i]     = o0;
    out[2 * i + 1] = o1;
}

extern "C" void kernel_launch(void* const* d_in, const int* in_sizes, int n_in,
                              void* d_out, int out_size, void* d_ws, size_t ws_size,
                              hipStream_t stream) {
    const float4* a = (const float4*)d_in[0];
    const float4* b = (const float4*)d_in[1];
    float4* out = (float4*)d_out;
    int n_groups = in_sizes[0] / 8;   // 1024*4096 groups of 8 bit-floats
    int block = 256;
    int grid = (n_groups + block - 1) / block;
    fp8_mul_kernel<<<grid, block, 0, stream>>>(a, b, out, n_groups);
}

// Round 2
// 299.074 us; speedup vs baseline: 1.0117x; 1.0117x over previous
//
#include <hip/hip_runtime.h>

// FP8 E4M3 bit-level multiplier — unit-stride layout.
// Each thread owns ONE float4 (half a bit-group). Lane pairs (2k, 2k+1)
// exchange compacted 4-bit nibbles via __shfl_xor(.,1) so both lanes hold the
// full 8-bit a/b codes; each computes the product redundantly and stores the
// 4 output bits it owns. All global loads/stores are lane-unit-stride 16B.

#define BIAS 7

__device__ __forceinline__ int rne_rshift(int M, int sh) {
    // round-to-nearest-even right shift of non-negative M by sh >= 0
    int q = M >> sh;
    int rem = M - (q << sh);
    int half = (1 << sh) >> 1;           // 2^(sh-1), 0 when sh==0
    int up = ((rem > half) | ((rem == half) & (q & 1))) & (sh > 0);
    return q + up;
}

__device__ __forceinline__ int fp8_mul_byte(int a8, int b8) {
    int sa = a8 >> 7,        sb_ = b8 >> 7;
    int ea = (a8 >> 3) & 15, eb = (b8 >> 3) & 15;
    int ma = a8 & 7,         mb = b8 & 7;

    int sig_a = (ea == 0) ? ma : (ma + 8);
    int sig_b = (eb == 0) ? mb : (mb + 8);
    int exa = ((ea == 0) ? 1 : ea) - BIAS;
    int exb = ((eb == 0) ? 1 : eb) - BIAS;

    int M = sig_a * sig_b;              // exact product, <= 225
    int E = exa + exb - 6;              // value = M * 2^E

    int p = (M > 0) ? (31 - __clz(M)) : 0;
    int eb_out = E + p + BIAS;

    // normal path (eb_out >= 1): RNE round to 3 mantissa bits
    int sh  = p - 3;
    int shp = (sh > 0) ? sh : 0;
    int lsh = (sh < 0) ? -sh : 0;
    int mant4 = rne_rshift(M, shp) << lsh;   // in [8, 16]
    int carry = mant4 >> 4;
    if (mant4 == 16) mant4 = 8;
    int e_n = eb_out + carry;
    int m_n = mant4 - 8;
    if (e_n >= 16) { e_n = 15; m_n = 7; }    // overflow -> NaN

    // subnormal path (eb_out <= 0): mant = RNE(M * 2^(E+9))
    int t = E + 9;
    int rsh   = (-t < 0) ? 0 : ((-t > 30) ? 30 : -t);
    int lsh_s = (t > 0) ? t : 0;
    int mant_s = rne_rshift(M, rsh) << lsh_s;
    int e_s = (mant_s >= 8) ? 1 : 0;
    int m_s = (mant_s >= 8) ? 0 : mant_s;

    int is_sub = (eb_out <= 0);
    int e_o = is_sub ? e_s : e_n;
    int m_o = is_sub ? m_s : m_n;
    if (M == 0) { e_o = 0; m_o = 0; }
    int s_o = sa ^ sb_;
    return (s_o << 7) | (e_o << 3) | m_o;
}

__global__ void __launch_bounds__(256)
fp8_mul_kernel(const uint4* __restrict__ a, const uint4* __restrict__ b,
               float4* __restrict__ out, int n_vec) {
    int j = blockIdx.x * blockDim.x + threadIdx.x;
    if (j >= n_vec) return;

    uint4 av = a[j];
    uint4 bv = b[j];

    // compact the 4 bit-floats (0.0f or 1.0f) into a nibble, a|b packed
    int na = ((av.x != 0) << 3) | ((av.y != 0) << 2) | ((av.z != 0) << 1) | (int)(av.w != 0);
    int nb = ((bv.x != 0) << 3) | ((bv.y != 0) << 2) | ((bv.z != 0) << 1) | (int)(bv.w != 0);
    int own = na | (nb << 4);
    int pp  = __shfl_xor(own, 1);        // partner lane's nibbles

    int odd = j & 1;                      // lane parity == group-half parity
    // even lane holds [s,e3,e2,e1] (high nibble), odd holds [e0,m2,m1,m0]
    int a8 = odd ? (((pp  & 0xF) << 4) |  (own & 0xF))
                 : (((own & 0xF) << 4) |  (pp  & 0xF));
    int b8 = odd ? ((((pp  >> 4) & 0xF) << 4) | ((own >> 4) & 0xF))
                 : ((((own >> 4) & 0xF) << 4) | ((pp  >> 4) & 0xF));

    int r = fp8_mul_byte(a8, b8);

    int sbit = odd ? 3 : 7;               // which 4 result bits this lane stores
    float4 o;
    o.x = (float)((r >> sbit)       & 1);
    o.y = (float)((r >> (sbit - 1)) & 1);
    o.z = (float)((r >> (sbit - 2)) & 1);
    o.w = (float)((r >> (sbit - 3)) & 1);
    out[j] = o;
}

extern "C" void kernel_launch(void* const* d_in, const int* in_sizes, int n_in,
                              void* d_out, int out_size, void* d_ws, size_t ws_size,
                              hipStream_t stream) {
    const uint4* a = (const uint4*)d_in[0];
    const uint4* b = (const uint4*)d_in[1];
    float4* out = (float4*)d_out;
    int n_vec = in_sizes[0] / 4;          // one float4 (half group) per thread
    int block = 256;
    int grid = (n_vec + block - 1) / block;
    fp8_mul_kernel<<<grid, block, 0, stream>>>(a, b, out, n_vec);
}